// Round 3
// baseline (97.657 us; speedup 1.0000x reference)
//
#include <hip/hip_runtime.h>

// out[n,m] = exp(-0.5 * sum_d (x[n,d]-c[m,d])^2 / s2[m,d]) / sqrt((2pi)^D * prod s2[m,d])
// Fast path (per-center d-uniform variance, true for bench sigma==1):
//   out = exp2( L2E*(x.a) + q*r2[n] + c0 ),  a = c/s2, q = -0.5*L2E/s2,
//   c0 = -0.5*L2E*(c.a) - 0.5*(D*log2(2pi) + sum log2 s2)
// x rows are loop-uniform -> SMEM (s_load) served; rows processed in PAIRS so
// both rows' scalar loads issue under one waitcnt (latency halved per output).

#define N_  16384
#define M_  1024
#define D_  32
#define NT  32      // n-rows per block -> grid = 4 x 512 = 2048 blocks = 8/CU
#define BLK 256     // threads per block = m-tile width

typedef float v2f __attribute__((ext_vector_type(2)));

__global__ __launch_bounds__(BLK) void rbf_kernel(
    const float* __restrict__ x, const float* __restrict__ centers,
    const float* __restrict__ sigma, float* __restrict__ out)
{
    const int tid = threadIdx.x;
    const int m   = blockIdx.x * BLK + tid;
    const int n0  = blockIdx.y * NT;

    __shared__ float r2s[NT];   // 128 B

    if (tid < NT) {
        const float4* xr = (const float4*)(x + (size_t)(n0 + tid) * D_);
        float a0 = 0.f, a1 = 0.f, a2 = 0.f, a3 = 0.f;
        #pragma unroll
        for (int k = 0; k < D_ / 4; ++k) {
            float4 v = xr[k];
            a0 = fmaf(v.x, v.x, a0); a1 = fmaf(v.y, v.y, a1);
            a2 = fmaf(v.z, v.z, a2); a3 = fmaf(v.w, v.w, a3);
        }
        r2s[tid] = (a0 + a1) + (a2 + a3);
    }
    __syncthreads();

    const float L2E      = 1.4426950408889634f;   // log2(e)
    const float LOG2_2PI = 2.6514961294723187f;   // log2(2*pi)

    // sigma scan: d-uniform check + log-determinant (exactly 0 for sigma==1)
    float s2_0 = 0.f, ld = 0.f;
    bool uf = true;
    {
        const float* sg = sigma + (size_t)m * D_;
        #pragma unroll
        for (int d = 0; d < D_; ++d) {
            float s  = sg[d];
            float s2 = s * s;
            if (d == 0) s2_0 = s2;
            uf = uf && (s2 == s2_0);
            ld += log2f(s2);
        }
    }

    if (__all((int)uf)) {
        const float w0 = 1.0f / s2_0;
        v2f av[D_ / 2];
        float b = 0.f;
        {
            const v2f* cg = (const v2f*)(centers + (size_t)m * D_);
            #pragma unroll
            for (int j = 0; j < D_ / 2; ++j) {
                v2f c = cg[j];
                v2f a = c * w0;
                av[j] = a;
                b = fmaf(c.x, a.x, b);
                b = fmaf(c.y, a.y, b);
            }
        }
        const float c0 = fmaf(-0.5f * L2E, b, -0.5f * (D_ * LOG2_2PI + ld));
        const float qc = -0.5f * L2E * w0;

        float* o0 = out + (size_t)n0 * M_ + m;
        #pragma unroll 1
        for (int i = 0; i < NT; i += 2) {
            const v2f* xr0 = (const v2f*)(x + (size_t)(n0 + i) * D_);  // uniform -> s_load
            const v2f* xr1 = xr0 + (D_ / 2);
            v2f p0 = {0.f,0.f}, p1 = {0.f,0.f};
            v2f q0 = {0.f,0.f}, q1 = {0.f,0.f};
            #pragma unroll
            for (int j = 0; j < D_ / 2; j += 2) {
                p0 += xr0[j]     * av[j];
                p1 += xr0[j + 1] * av[j + 1];
                q0 += xr1[j]     * av[j];
                q1 += xr1[j + 1] * av[j + 1];
            }
            v2f ps = p0 + p1;
            v2f qs = q0 + q1;
            float f0 = fmaf(L2E, ps.x + ps.y, fmaf(qc, r2s[i],     c0));
            float f1 = fmaf(L2E, qs.x + qs.y, fmaf(qc, r2s[i + 1], c0));
            __builtin_nontemporal_store(__builtin_amdgcn_exp2f(f0), o0 + (size_t)i * M_);
            __builtin_nontemporal_store(__builtin_amdgcn_exp2f(f1), o0 + (size_t)(i + 1) * M_);
        }
    } else {
        // general path: correct, frugal on registers (reload per row; L1/L2-hot)
        const float c0 = -0.5f * (D_ * LOG2_2PI + ld);
        const float* cg = centers + (size_t)m * D_;
        const float* sg = sigma   + (size_t)m * D_;
        #pragma unroll 1
        for (int i = 0; i < NT; ++i) {
            const float* xr = x + (size_t)(n0 + i) * D_;
            float a0 = 0.f, a1 = 0.f;
            #pragma unroll
            for (int d = 0; d < D_; d += 2) {
                float s0 = sg[d], s1 = sg[d + 1];
                float t0 = xr[d]     - cg[d];
                float t1 = xr[d + 1] - cg[d + 1];
                a0 = fmaf(t0 * (1.0f / (s0 * s0)), t0, a0);
                a1 = fmaf(t1 * (1.0f / (s1 * s1)), t1, a1);
            }
            float f = fmaf(-0.5f * L2E, a0 + a1, c0);
            out[(size_t)(n0 + i) * M_ + m] = __builtin_amdgcn_exp2f(f);
        }
    }
}

extern "C" void kernel_launch(void* const* d_in, const int* in_sizes, int n_in,
                              void* d_out, int out_size, void* d_ws, size_t ws_size,
                              hipStream_t stream) {
    const float* x = (const float*)d_in[0];
    const float* c = (const float*)d_in[1];
    const float* s = (const float*)d_in[2];
    float* out = (float*)d_out;
    dim3 grid(M_ / BLK, N_ / NT);
    rbf_kernel<<<grid, BLK, 0, stream>>>(x, c, s, out);
}

// Round 4
// 94.579 us; speedup vs baseline: 1.0325x; 1.0325x over previous
//
#include <hip/hip_runtime.h>

// out[n,m] = exp(-0.5 * sum_d (x[n,d]-c[m,d])^2 / s2[m,d]) / sqrt((2pi)^D * prod s2[m,d])
// Fast path (per-center d-uniform variance; true for bench sigma==1):
//   out = exp2( L2E*(x.a) + qc*r2[n] + c0 ),  a = c/s2, qc = -0.5*L2E/s2,
//   c0 = -0.5*L2E*(c.a) - 0.5*(D*log2(2pi) + sum log2 s2),  r2[n] = sum_d x^2
//
// KEY FIX (round 4): the per-m coefficient vector A[16] (v2f) is pinned into
// VGPRs with an asm register barrier. Without it the compiler sinks the
// centers loads into the row loop (VGPR_Count was 44 < the 32 regs A needs),
// re-fetching 128 B/lane every row -> loop-carried L1/L2 latency ~330 cyc/row
// -> the measured ~35 us. __launch_bounds__(256,4) allows 128 VGPRs.

#define N_  16384
#define M_  1024
#define D_  32
#define NT  64      // grid = (4, 256) = 1024 blocks = 4 blocks/CU exactly
#define BLK 256

typedef float v2f __attribute__((ext_vector_type(2)));
#define PIN(v) asm volatile("" : "+v"(v))

__global__ __launch_bounds__(BLK, 4) void rbf_kernel(
    const float* __restrict__ x, const float* __restrict__ centers,
    const float* __restrict__ sigma, float* __restrict__ out)
{
    const int tid = threadIdx.x;
    const int m   = blockIdx.x * BLK + tid;
    const int n0  = blockIdx.y * NT;

    __shared__ float r2s[NT];

    if (tid < NT) {   // one full wave computes r2 for the tile's rows
        const float4* xr = (const float4*)(x + (size_t)(n0 + tid) * D_);
        float a0 = 0.f, a1 = 0.f, a2 = 0.f, a3 = 0.f;
        #pragma unroll
        for (int k = 0; k < D_ / 4; ++k) {
            float4 v = xr[k];
            a0 = fmaf(v.x, v.x, a0); a1 = fmaf(v.y, v.y, a1);
            a2 = fmaf(v.z, v.z, a2); a3 = fmaf(v.w, v.w, a3);
        }
        r2s[tid] = (a0 + a1) + (a2 + a3);
    }
    __syncthreads();

    const float L2E      = 1.4426950408889634f;   // log2(e)
    const float LOG2_2PI = 2.6514961294723187f;   // log2(2*pi)

    // sigma scan: d-uniform check + log-determinant (exactly 0 for sigma==1)
    float s2_0 = 0.f, ld = 0.f;
    bool uf = true;
    {
        const float* sg = sigma + (size_t)m * D_;
        #pragma unroll
        for (int d = 0; d < D_; ++d) {
            float s  = sg[d];
            float s2 = s * s;
            if (d == 0) s2_0 = s2;
            uf = uf && (s2 == s2_0);
            ld += log2f(s2);
        }
    }

    if (__all((int)uf)) {
        const float w0 = 1.0f / s2_0;
        v2f A[D_ / 2];
        float b = 0.f;
        {
            const v2f* cg = (const v2f*)(centers + (size_t)m * D_);
            #pragma unroll
            for (int j = 0; j < D_ / 2; ++j) {
                v2f c = cg[j];
                v2f a = c * w0;
                A[j] = a;
                b = fmaf(c.x, a.x, b);
                b = fmaf(c.y, a.y, b);
            }
        }
        // Register barrier: after this the compiler cannot rematerialize A
        // from the centers loads -> A stays VGPR-resident across the loop.
        #pragma unroll
        for (int j = 0; j < D_ / 2; ++j) PIN(A[j]);

        const float c0 = fmaf(-0.5f * L2E, b, -0.5f * (D_ * LOG2_2PI + ld));
        const float qc = -0.5f * L2E * w0;

        float* o0 = out + (size_t)n0 * M_ + m;
        #pragma unroll 1
        for (int i = 0; i < NT; i += 2) {
            const v2f* xa = (const v2f*)(x + (size_t)(n0 + i) * D_);  // uniform
            const v2f* xb = xa + (D_ / 2);
            v2f p0 = {0.f,0.f}, p1 = {0.f,0.f};
            v2f q0 = {0.f,0.f}, q1 = {0.f,0.f};
            #pragma unroll
            for (int j = 0; j < D_ / 2; j += 2) {
                p0 += xa[j]     * A[j];       // v_pk_fma_f32
                p1 += xa[j + 1] * A[j + 1];
                q0 += xb[j]     * A[j];
                q1 += xb[j + 1] * A[j + 1];
            }
            v2f ps = p0 + p1;
            v2f qs = q0 + q1;
            float f0 = fmaf(L2E, ps.x + ps.y, fmaf(qc, r2s[i],     c0));
            float f1 = fmaf(L2E, qs.x + qs.y, fmaf(qc, r2s[i + 1], c0));
            __builtin_nontemporal_store(__builtin_amdgcn_exp2f(f0), o0 + (size_t)i * M_);
            __builtin_nontemporal_store(__builtin_amdgcn_exp2f(f1), o0 + (size_t)(i + 1) * M_);
        }
    } else {
        // general path: correct for arbitrary sigma, register-frugal
        const float c0 = -0.5f * (D_ * LOG2_2PI + ld);
        const float* cg = centers + (size_t)m * D_;
        const float* sg = sigma   + (size_t)m * D_;
        #pragma unroll 1
        for (int i = 0; i < NT; ++i) {
            const float* xr = x + (size_t)(n0 + i) * D_;
            float a0 = 0.f, a1 = 0.f;
            #pragma unroll
            for (int d = 0; d < D_; d += 2) {
                float s0 = sg[d], s1 = sg[d + 1];
                float t0 = xr[d]     - cg[d];
                float t1 = xr[d + 1] - cg[d + 1];
                a0 = fmaf(t0 * (1.0f / (s0 * s0)), t0, a0);
                a1 = fmaf(t1 * (1.0f / (s1 * s1)), t1, a1);
            }
            float f = fmaf(-0.5f * L2E, a0 + a1, c0);
            out[(size_t)(n0 + i) * M_ + m] = __builtin_amdgcn_exp2f(f);
        }
    }
}

extern "C" void kernel_launch(void* const* d_in, const int* in_sizes, int n_in,
                              void* d_out, int out_size, void* d_ws, size_t ws_size,
                              hipStream_t stream) {
    const float* x = (const float*)d_in[0];
    const float* c = (const float*)d_in[1];
    const float* s = (const float*)d_in[2];
    float* out = (float*)d_out;
    dim3 grid(M_ / BLK, N_ / NT);
    rbf_kernel<<<grid, BLK, 0, stream>>>(x, c, s, out);
}